// Round 1
// baseline (544.935 us; speedup 1.0000x reference)
//
#include <hip/hip_runtime.h>

// Problem constants (from reference)
#define BATCH 2048
#define T 512
#define NF 10
#define HID 30
#define S3T 1536          // 3*T sequence length after reshape/transpose
#define FEAT_PER_B 15360  // 10*1536 features per batch element
// Workspace: BATCH * FEAT_PER_B * 2 = 62,914,560 bytes (f16 xpair)
// Layout: xpair[b][p][s][e] (p<5, s<1536, e<2) = f16 x[b][s][2p+e].
// One uint4 (16B) at stream p, chunk c = d-pair (2p,2p+1) for steps 4c..4c+3.

typedef _Float16 v2h __attribute__((ext_vector_type(2)));

#define LOG2E 1.44269504088896f

__device__ __forceinline__ float fexp(float x) {
    return __builtin_amdgcn_exp2f(x * LOG2E);   // v_exp_f32
}
__device__ __forceinline__ float frcp(float x) {
    return __builtin_amdgcn_rcpf(x);            // v_rcp_f32
}

// R19: combine the two 32-lane halves' partial dots. v_permlane32_swap is a
// VALU op (~2cyc) — NOT the DS pipe — so the combine costs ~10 cyc on the
// chain vs ~60+ for ds_bpermute. r0+r1 = own partial + partner partial on
// BOTH halves (bitwise identical result on lane k and k+32).
__device__ __forceinline__ float half_sum(float a) {
    unsigned ua = __builtin_bit_cast(unsigned, a);
    auto r = __builtin_amdgcn_permlane32_swap(ua, ua, false, false);
    return __builtin_bit_cast(float, (unsigned)r[0]) +
           __builtin_bit_cast(float, (unsigned)r[1]);
}

// Kernel 1: transpose-through-LDS [R15: 89 -> ~19us], f16 out [R16].
__global__ void __launch_bounds__(512)
feat_kernel(const int* __restrict__ atom_i,
            const int* __restrict__ atom_j,
            const float* __restrict__ dist,
            const float* __restrict__ emb,
            uint4* __restrict__ xpair8) {
    __shared__ float lf[512 * 31 + 30];   // slot(t,c) = t*31 + c
    const int b = blockIdx.x;
    const int t = threadIdx.x;

    {
        const int bt = b * T + t;
        const int ai = atom_i[bt];
        const int aj = atom_j[bt];
        const float dd = dist[bt];
        const float mi = (ai != 0) ? 1.0f : 0.0f;
        const float mj = (aj != 0) ? 1.0f : 0.0f;
        const float* ei = &emb[ai * NF];
        const float* ej = &emb[aj * NF];
        float* row = &lf[t * 31];
#pragma unroll
        for (int c = 0; c < NF; ++c) row[c] = mi * ei[c];
#pragma unroll
        for (int c = 0; c < NF; ++c) row[10 + c] = mj * ej[c];
#pragma unroll
        for (int c = 0; c < NF; ++c) {
            float ctr = (float)(c + 1) * 0.7f;
            float df = ctr - dd;
            row[20 + c] = mi * fexp(-df * df);
        }
    }
    __syncthreads();

    uint4* ob = xpair8 + (long)b * 1920;
    for (int o = t; o < 1920; o += 512) {
        unsigned p  = (unsigned)o / 384u;
        unsigned c4 = (unsigned)o - p * 384u;
        union { _Float16 h[8]; uint4 u; } pk;
#pragma unroll
        for (int kx = 0; kx < 8; ++kx) {
            unsigned s = 4u * c4 + (unsigned)(kx >> 1);
            unsigned e = (unsigned)(kx & 1);
            unsigned f = (2u * p + e) * 1536u + s;
            unsigned tt = f / 30u;            // compiler -> magic mul
            unsigned cc = f - tt * 30u;
            pk.h[kx] = (_Float16)lf[tt * 31u + cc];
        }
        ob[o] = pk.u;
    }
}

// One GRU step (R19 split-half mapping): lane k AND lane k+32 both own unit
// k of the wave's single batch. lo half accumulates hh j-pairs 0-7 + ih
// pairs 0-2 (+ biases); hi half hh pairs 8-15 (pair 15 zero-padded) + ih
// pairs 3-4 (3rd slot zero-padded). ds_read issued FIRST, ih dots (register
// only) issue during its flight, hh chain is 8 deep (was 20), then 4
// permlane32_swap combines. Each half keeps a private 32-slot h copy in LDS
// (values bitwise identical), so no cross-half traffic. Trailing wavefront
// fence = compile-time LDS ordering only [R10].
#define STEP(PAR, XQ, IDX)                                                   \
    {                                                                        \
        const uint4* hv = (const uint4*)&hbuf16[PAR][half * 48];             \
        uint4 t0 = hv[0], t1 = hv[1];                                        \
        v2h xc[3];                                                           \
        _Pragma("unroll")                                                    \
        for (int pp = 0; pp < 3; ++pp) {                                     \
            unsigned w = ((const unsigned*)&XQ[pp])[IDX];                    \
            __builtin_memcpy(&xc[pp], &w, 4);                                \
        }                                                                    \
        float ar = brf, az = bzf, ai = bif, ah = bhf;                        \
        _Pragma("unroll")                                                    \
        for (int d = 0; d < 3; ++d) {                                        \
            ar = __builtin_amdgcn_fdot2(wir[d], xc[d], ar, false);           \
            az = __builtin_amdgcn_fdot2(wiz[d], xc[d], az, false);           \
            ai = __builtin_amdgcn_fdot2(win[d], xc[d], ai, false);           \
        }                                                                    \
        v2h hj[8];                                                           \
        __builtin_memcpy(&hj[0], &t0, 16);                                   \
        __builtin_memcpy(&hj[4], &t1, 16);                                   \
        _Pragma("unroll")                                                    \
        for (int j = 0; j < 8; ++j) {                                        \
            ar = __builtin_amdgcn_fdot2(whr[j], hj[j], ar, false);           \
            az = __builtin_amdgcn_fdot2(whz[j], hj[j], az, false);           \
            ah = __builtin_amdgcn_fdot2(whn[j], hj[j], ah, false);           \
        }                                                                    \
        ar = half_sum(ar); az = half_sum(az);                                \
        ai = half_sum(ai); ah = half_sum(ah);                                \
        float er = __builtin_amdgcn_exp2f(ar);                               \
        float ez = __builtin_amdgcn_exp2f(az);                               \
        float rg = frcp(1.0f + er);                                          \
        float zg = frcp(1.0f + ez);                                          \
        float ng =                                                           \
            2.0f * frcp(1.0f + __builtin_amdgcn_exp2f(ai + rg * ah)) - 1.0f; \
        h = ng + zg * (h - ng);                                              \
        hbuf16[(PAR) ^ 1][half * 32 + k] = (_Float16)h;                      \
        __builtin_amdgcn_fence(__ATOMIC_ACQ_REL, "wavefront");               \
    }

// Kernel 2: GRU recurrence — R19: 1 batch per wave, 2048 single-wave blocks
// -> 2 waves/SIMD co-resident (was 1): the second wave's issue fills the
// first wave's LDS-round-trip + transcendental-chain stalls, which rocprof
// showed to be ~70% of the 608 cyc/step wall (VALUBusy 62% is the gfx94x
// 2x-inflated formula; real issue ~31%). Per-wave fdot2/step 60 -> 33 and
// dot chain 20 -> 8 via the half-split. waves_per_eu(2,2): VGPR cap 256,
// usage ~110 — weights stay resident for both waves.
__attribute__((amdgpu_waves_per_eu(2, 2)))
__global__ void __launch_bounds__(64)
gru_kernel(const _Float16* __restrict__ xpair,
           const float* __restrict__ W_ih,   // [90,10]
           const float* __restrict__ W_hh,   // [90,30]
           const float* __restrict__ b_ih,   // [90]
           const float* __restrict__ b_hh,   // [90]
           const float* __restrict__ W_out,  // [1,30]
           const float* __restrict__ b_out,  // [1]
           float* __restrict__ out) {
    __shared__ __align__(16) _Float16 hbuf16[2][64];
    const int lane = threadIdx.x;
    const int half = lane >> 5;
    const int k    = lane & 31;
    const bool active = (k < HID);
    const int kk = active ? k : (HID - 1);
    const int b = blockIdx.x;

    const float SRZ = -LOG2E;          // sigmoid(x) = rcp(1+exp2(-L x))
    const float SN  = -2.0f * LOG2E;   // tanh(u) = 2 rcp(1+exp2(-2L u)) - 1

    // hh weights: 8 v2h per gate per lane = global j-pairs half*8 .. +7.
    // Pair 15 (cols 30,31) is zero via scale mask. Prescaled f32 -> RNE f16.
    v2h whr[8], whz[8], whn[8];
    {
        const float* Rr = &W_hh[(0 * HID + kk) * HID];
        const float* Rz = &W_hh[(1 * HID + kk) * HID];
        const float* Rn = &W_hh[(2 * HID + kk) * HID];
        const int jb = half * 8;
#pragma unroll
        for (int j = 0; j < 8; ++j) {
            const int c  = (jb + j) * 2;
            const int cs = (c < HID) ? c : 0;       // safe addr
            const float mrz = (c < HID) ? SRZ : 0.0f;
            const float mn  = (c < HID) ? SN  : 0.0f;
            whr[j] = (v2h){(_Float16)(Rr[cs] * mrz), (_Float16)(Rr[cs + 1] * mrz)};
            whz[j] = (v2h){(_Float16)(Rz[cs] * mrz), (_Float16)(Rz[cs + 1] * mrz)};
            whn[j] = (v2h){(_Float16)(Rn[cs] * mn),  (_Float16)(Rn[cs + 1] * mn)};
        }
    }
    // ih weights: 3 v2h per gate per lane = d-pairs half*3 .. +2 (pair 5 = 0).
    v2h wir[3], wiz[3], win[3];
    const int db = half * 3;
    {
        const float* Rr = &W_ih[(0 * HID + kk) * NF];
        const float* Rz = &W_ih[(1 * HID + kk) * NF];
        const float* Rn = &W_ih[(2 * HID + kk) * NF];
#pragma unroll
        for (int i = 0; i < 3; ++i) {
            const int d  = db + i;
            const int dd = (d < 5) ? d * 2 : 0;
            const float mrz = (d < 5) ? SRZ : 0.0f;
            const float mn  = (d < 5) ? SN  : 0.0f;
            wir[i] = (v2h){(_Float16)(Rr[dd] * mrz), (_Float16)(Rr[dd + 1] * mrz)};
            wiz[i] = (v2h){(_Float16)(Rz[dd] * mrz), (_Float16)(Rz[dd + 1] * mrz)};
            win[i] = (v2h){(_Float16)(Rn[dd] * mn),  (_Float16)(Rn[dd + 1] * mn)};
        }
    }
    // Biases: counted ONCE per combined sum -> seed lo half only.
    const float en  = (half == 0) ? 1.0f : 0.0f;
    const float brf = en * SRZ * (b_ih[0 * HID + kk] + b_hh[0 * HID + kk]);
    const float bzf = en * SRZ * (b_ih[1 * HID + kk] + b_hh[1 * HID + kk]);
    const float bif = en * SN * b_ih[2 * HID + kk];  // n stays split:
    const float bhf = en * SN * b_hh[2 * HID + kk];  // n uses ai + rg*ah

    // 3 chunk streams per lane: lo lanes use d-pair streams {0,1,2}, hi
    // lanes {3,4,4-dup} (dup is multiplied by the zero pad weight).
    const _Float16* xb = xpair + (long)b * FEAT_PER_B;
    const uint4* xa[3];
#pragma unroll
    for (int i = 0; i < 3; ++i) {
        int s = db + i;
        if (s > 4) s = 4;
        xa[i] = (const uint4*)(xb + s * 3072);
    }

    hbuf16[0][lane] = (_Float16)0.0f;
    hbuf16[1][lane] = (_Float16)0.0f;
    __builtin_amdgcn_fence(__ATOMIC_ACQ_REL, "wavefront");

    float h = 0.0f;
    uint4 xq0[3], xq1[3];
#pragma unroll
    for (int p = 0; p < 3; ++p) xq0[p] = xa[p][0];

    // 384 chunks of 4 steps, ping-pong pairs (xq0/xq1 alternate roles — no
    // register rotation [R18]). 384 is even; prefetch c2+1 always in range,
    // tail prefetch c2+2 clamps to 383.
    for (int c2 = 0; c2 < 384; c2 += 2) {
#pragma unroll
        for (int p = 0; p < 3; ++p) xq1[p] = xa[p][c2 + 1];
        STEP(0, xq0, 0);
        STEP(1, xq0, 1);
        STEP(0, xq0, 2);
        STEP(1, xq0, 3);
        const int cn = (c2 + 2 < 384) ? (c2 + 2) : 383;
#pragma unroll
        for (int p = 0; p < 3; ++p) xq0[p] = xa[p][cn];
        STEP(0, xq1, 0);
        STEP(1, xq1, 1);
        STEP(0, xq1, 2);
        STEP(1, xq1, 3);
    }

    // out[b] = relu(h . W_out + b_out); both halves hold identical h ->
    // reduce the lower half only.
    float v = active ? h * W_out[kk] : 0.0f;
#pragma unroll
    for (int off = 16; off; off >>= 1) v += __shfl_xor(v, off, 32);
    if (lane == 0) {
        float o = v + b_out[0];
        out[b] = o > 0.0f ? o : 0.0f;
    }
}

extern "C" void kernel_launch(void* const* d_in, const int* in_sizes, int n_in,
                              void* d_out, int out_size, void* d_ws, size_t ws_size,
                              hipStream_t stream) {
    const int* atom_i   = (const int*)d_in[0];
    const int* atom_j   = (const int*)d_in[1];
    const float* dist   = (const float*)d_in[2];
    const float* emb    = (const float*)d_in[3];
    const float* W_ih   = (const float*)d_in[4];
    const float* W_hh   = (const float*)d_in[5];
    const float* b_ih   = (const float*)d_in[6];
    const float* b_hh   = (const float*)d_in[7];
    const float* W_out  = (const float*)d_in[8];
    const float* b_out  = (const float*)d_in[9];
    float* out = (float*)d_out;
    _Float16* xpair = (_Float16*)d_ws;   // 62,914,560 B

    feat_kernel<<<BATCH, 512, 0, stream>>>(atom_i, atom_j, dist, emb,
                                           (uint4*)xpair);
    gru_kernel<<<BATCH, 64, 0, stream>>>(xpair, W_ih, W_hh, b_ih, b_hh,
                                         W_out, b_out, out);
}

// Round 3
// 469.608 us; speedup vs baseline: 1.1604x; 1.1604x over previous
//
#include <hip/hip_runtime.h>

// Problem constants (from reference)
#define BATCH 2048
#define T 512
#define NF 10
#define HID 30
#define S3T 1536          // 3*T sequence length after reshape/transpose
#define FEAT_PER_B 15360  // 10*1536 features per batch element
// Workspace: BATCH * FEAT_PER_B * 2 = 62,914,560 bytes (f16 xpair)
// Layout: xpair[b][p][s][e] (p<5, s<1536, e<2) = f16 x[b][s][2p+e].
// One uint4 (16B) at stream p, chunk c = d-pair (2p,2p+1) for steps 4c..4c+3.

typedef _Float16 v2h __attribute__((ext_vector_type(2)));

#define LOG2E 1.44269504088896f

__device__ __forceinline__ float fexp(float x) {
    return __builtin_amdgcn_exp2f(x * LOG2E);   // v_exp_f32
}
__device__ __forceinline__ float frcp(float x) {
    return __builtin_amdgcn_rcpf(x);            // v_rcp_f32
}

// DPP ctrl encodings
#define DPP_QPERM_XOR1 0xB1   // quad_perm [1,0,3,2]
#define DPP_ROR2       0x122  // row_ror:2  (1 pair)
#define DPP_ROR4       0x124  // row_ror:4  (2 pairs)
#define DPP_ROR8       0x128  // row_ror:8  (4 pairs)

// R21 compile fix: dpp_ctrl must be an ICE at the call site -> template
// parameter, not a runtime arg.
template <int CTRL>
__device__ __forceinline__ unsigned dppmov(unsigned v) {
    return (unsigned)__builtin_amdgcn_update_dpp(0, (int)v, CTRL, 0xF, 0xF,
                                                 false);
}

// Kernel 1: transpose-through-LDS [R15: 89 -> ~19us], f16 out [R16].
__global__ void __launch_bounds__(512)
feat_kernel(const int* __restrict__ atom_i,
            const int* __restrict__ atom_j,
            const float* __restrict__ dist,
            const float* __restrict__ emb,
            uint4* __restrict__ xpair8) {
    __shared__ float lf[512 * 31 + 30];   // slot(t,c) = t*31 + c
    const int b = blockIdx.x;
    const int t = threadIdx.x;

    {
        const int bt = b * T + t;
        const int ai = atom_i[bt];
        const int aj = atom_j[bt];
        const float dd = dist[bt];
        const float mi = (ai != 0) ? 1.0f : 0.0f;
        const float mj = (aj != 0) ? 1.0f : 0.0f;
        const float* ei = &emb[ai * NF];
        const float* ej = &emb[aj * NF];
        float* row = &lf[t * 31];
#pragma unroll
        for (int c = 0; c < NF; ++c) row[c] = mi * ei[c];
#pragma unroll
        for (int c = 0; c < NF; ++c) row[10 + c] = mj * ej[c];
#pragma unroll
        for (int c = 0; c < NF; ++c) {
            float ctr = (float)(c + 1) * 0.7f;
            float df = ctr - dd;
            row[20 + c] = mi * fexp(-df * df);
        }
    }
    __syncthreads();

    uint4* ob = xpair8 + (long)b * 1920;
    for (int o = t; o < 1920; o += 512) {
        unsigned p  = (unsigned)o / 384u;
        unsigned c4 = (unsigned)o - p * 384u;
        union { _Float16 h[8]; uint4 u; } pk;
#pragma unroll
        for (int kx = 0; kx < 8; ++kx) {
            unsigned s = 4u * c4 + (unsigned)(kx >> 1);
            unsigned e = (unsigned)(kx & 1);
            unsigned f = (2u * p + e) * 1536u + s;
            unsigned tt = f / 30u;            // compiler -> magic mul
            unsigned cc = f - tt * 30u;
            pk.h[kx] = (_Float16)lf[tt * 31u + cc];
        }
        ob[o] = pk.u;
    }
}

// One GRU step (R20/R21): h broadcast is a pure-VALU in-register all-gather
// — NO LDS, NO fences. cvt h->f16; quad-perm DPP + pack -> own v2h pair
// (intra-pair order parity-swizzled, absorbed by weight order); row_ror
// DPPs -> all 8 pairs of own 16-row; permlane16_swap -> the other row's 8
// pairs (row0<->row1, row2<->row3: half-local, so the 2-batch lane split is
// preserved). ~19 VALU ops (~38 cyc issue, ~20 cyc latency) replace the
// ~130-cyc ds_write/ds_read round trip + lgkm drains of R18. The per-lane
// reg->pair permutation is discovered at init (integer gather) and baked
// into the weight load order, so correctness is independent of ror
// direction / swap semantics. ih dots issue first (ready immediately),
// 16-pair hh dot chain follows the gather.
#define STEP(XQ, IDX)                                                        \
    {                                                                        \
        unsigned hf = (unsigned)__builtin_bit_cast(unsigned short,           \
                                                   (_Float16)h);             \
        unsigned nb = dppmov<DPP_QPERM_XOR1>(hf);                            \
        unsigned gg0 = hf | (nb << 16);                                      \
        unsigned gg1 = dppmov<DPP_ROR2>(gg0);                                \
        unsigned gg2 = dppmov<DPP_ROR4>(gg0);                                \
        unsigned gg3 = dppmov<DPP_ROR4>(gg1);                                \
        unsigned gg4 = dppmov<DPP_ROR8>(gg0);                                \
        unsigned gg5 = dppmov<DPP_ROR8>(gg1);                                \
        unsigned gg6 = dppmov<DPP_ROR8>(gg2);                                \
        unsigned gg7 = dppmov<DPP_ROR8>(gg3);                                \
        unsigned gg[8] = {gg0, gg1, gg2, gg3, gg4, gg5, gg6, gg7};           \
        v2h hp[16];                                                          \
        _Pragma("unroll")                                                    \
        for (int i = 0; i < 8; ++i) {                                        \
            auto rr = __builtin_amdgcn_permlane16_swap((unsigned)gg[i],      \
                                                       (unsigned)gg[i],      \
                                                       false, false);        \
            hp[i]     = __builtin_bit_cast(v2h, (unsigned)rr[0]);            \
            hp[8 + i] = __builtin_bit_cast(v2h, (unsigned)rr[1]);            \
        }                                                                    \
        v2h xc[5];                                                           \
        _Pragma("unroll")                                                    \
        for (int pp = 0; pp < 5; ++pp) {                                     \
            unsigned w = ((const unsigned*)&XQ[pp])[IDX];                    \
            __builtin_memcpy(&xc[pp], &w, 4);                                \
        }                                                                    \
        float ar = brf, az = bzf, ai = bif, ah = bhf;                        \
        _Pragma("unroll")                                                    \
        for (int d = 0; d < 5; ++d) {                                        \
            ar = __builtin_amdgcn_fdot2(wir[d], xc[d], ar, false);           \
            az = __builtin_amdgcn_fdot2(wiz[d], xc[d], az, false);           \
            ai = __builtin_amdgcn_fdot2(win[d], xc[d], ai, false);           \
        }                                                                    \
        _Pragma("unroll")                                                    \
        for (int j = 0; j < 16; ++j) {                                       \
            ar = __builtin_amdgcn_fdot2(whr[j], hp[j], ar, false);           \
            az = __builtin_amdgcn_fdot2(whz[j], hp[j], az, false);           \
            ah = __builtin_amdgcn_fdot2(whn[j], hp[j], ah, false);           \
        }                                                                    \
        float er = __builtin_amdgcn_exp2f(ar);                               \
        float ez = __builtin_amdgcn_exp2f(az);                               \
        float rg = frcp(1.0f + er);                                          \
        float zg = frcp(1.0f + ez);                                          \
        float ng =                                                           \
            2.0f * frcp(1.0f + __builtin_amdgcn_exp2f(ai + rg * ah)) - 1.0f; \
        h = ng + zg * (h - ng);                                              \
    }

// Kernel 2: GRU recurrence — R20/R21: back to the R18 mapping (2 batches
// per wave, full-dot per lane, 1024 single-wave blocks) which R19 proved is
// the issue-optimal layout (60 fdot2 + 3 trans per batch-step); the R18 LDS
// h-broadcast round trip (~130 cyc/step of the 608-cyc wall) is replaced
// by the DPP+permlane16_swap register all-gather above. h never leaves
// registers. waves_per_eu(1,1): grid supplies 1 wave/SIMD; full VGPR
// budget keeps all 63 weight v2h + 2x5 uint4 x-chunks resident.
__attribute__((amdgpu_waves_per_eu(1, 1)))
__global__ void __launch_bounds__(64)
gru_kernel(const _Float16* __restrict__ xpair,
           const float* __restrict__ W_ih,   // [90,10]
           const float* __restrict__ W_hh,   // [90,30]
           const float* __restrict__ b_ih,   // [90]
           const float* __restrict__ b_hh,   // [90]
           const float* __restrict__ W_out,  // [1,30]
           const float* __restrict__ b_out,  // [1]
           float* __restrict__ out) {
    const int lane = threadIdx.x;
    const int half = lane >> 5;
    const int k    = lane & 31;
    const bool active = (k < HID);
    const int kk = active ? k : (HID - 1);
    const int b = blockIdx.x * 2 + half;

    const float SRZ = -LOG2E;          // sigmoid(x) = rcp(1+exp2(-L x))
    const float SN  = -2.0f * LOG2E;   // tanh(u) = 2 rcp(1+exp2(-2L u)) - 1

    // Discover the gather's per-lane reg->pair permutation by running the
    // EXACT same DPP/permlane sequence on integer pair indices. pidx[i] =
    // which h-pair (0..15, relative to this 32-lane half) lands in hp[i].
    int pidx[16];
    {
        int p0 = (lane & 31) >> 1;
        unsigned q0 = (unsigned)p0;
        unsigned q1 = dppmov<DPP_ROR2>(q0);
        unsigned q2 = dppmov<DPP_ROR4>(q0);
        unsigned q3 = dppmov<DPP_ROR4>(q1);
        unsigned q4 = dppmov<DPP_ROR8>(q0);
        unsigned q5 = dppmov<DPP_ROR8>(q1);
        unsigned q6 = dppmov<DPP_ROR8>(q2);
        unsigned q7 = dppmov<DPP_ROR8>(q3);
        unsigned qs[8] = {q0, q1, q2, q3, q4, q5, q6, q7};
#pragma unroll
        for (int i = 0; i < 8; ++i) {
            auto rr = __builtin_amdgcn_permlane16_swap((unsigned)qs[i],
                                                       (unsigned)qs[i],
                                                       false, false);
            pidx[i]     = (int)rr[0];
            pidx[8 + i] = (int)rr[1];
        }
    }

    // hh weights: 16 v2h per gate, ordered to match the gather (pidx), with
    // intra-pair order swapped on odd lanes (their packed pair is
    // (h_odd, h_even)); fdot2 is a symmetric dot so this is exact. Pair 15
    // (h of the two inactive lanes 30,31) gets zero weights. Prescaled in
    // f32 (log2e folding: r/z x(-L), n x(-2L)) then RNE->f16.
    v2h whr[16], whz[16], whn[16];
    {
        const float* Rr = &W_hh[(0 * HID + kk) * HID];
        const float* Rz = &W_hh[(1 * HID + kk) * HID];
        const float* Rn = &W_hh[(2 * HID + kk) * HID];
        const bool odd = (lane & 1) != 0;
#pragma unroll
        for (int i = 0; i < 16; ++i) {
            const int p = pidx[i];
            const bool real = (p < 15);
            const int c = real ? 2 * p : 0;
            const float srz = real ? SRZ : 0.0f;
            const float sn  = real ? SN  : 0.0f;
            float r0 = Rr[c] * srz, r1 = Rr[c + 1] * srz;
            float z0 = Rz[c] * srz, z1 = Rz[c + 1] * srz;
            float n0 = Rn[c] * sn,  n1 = Rn[c + 1] * sn;
            if (odd) {
                float tt;
                tt = r0; r0 = r1; r1 = tt;
                tt = z0; z0 = z1; z1 = tt;
                tt = n0; n0 = n1; n1 = tt;
            }
            whr[i] = (v2h){(_Float16)r0, (_Float16)r1};
            whz[i] = (v2h){(_Float16)z0, (_Float16)z1};
            whn[i] = (v2h){(_Float16)n0, (_Float16)n1};
        }
    }
    // ih weights: 5 v2h per gate (d-pairs match xpair layout).
    v2h wir[5], wiz[5], win[5];
    {
        const float2* Rr = (const float2*)&W_ih[(0 * HID + kk) * NF];
        const float2* Rz = (const float2*)&W_ih[(1 * HID + kk) * NF];
        const float2* Rn = (const float2*)&W_ih[(2 * HID + kk) * NF];
#pragma unroll
        for (int d = 0; d < 5; ++d) {
            float2 tr = Rr[d], tz = Rz[d], tn = Rn[d];
            wir[d] = (v2h){(_Float16)(tr.x * SRZ), (_Float16)(tr.y * SRZ)};
            wiz[d] = (v2h){(_Float16)(tz.x * SRZ), (_Float16)(tz.y * SRZ)};
            win[d] = (v2h){(_Float16)(tn.x * SN),  (_Float16)(tn.y * SN)};
        }
    }
    // Biases (prescaled, f32 — fdot2's accumulator seed).
    const float brf = SRZ * (b_ih[0 * HID + kk] + b_hh[0 * HID + kk]);
    const float bzf = SRZ * (b_ih[1 * HID + kk] + b_hh[1 * HID + kk]);
    const float bif = SN * b_ih[2 * HID + kk];  // n biases stay split:
    const float bhf = SN * b_hh[2 * HID + kk];  // n uses ai + rg*ah

    // 5 chunk streams: xa[p][c] = uint4 = d-pair (2p,2p+1), steps 4c..4c+3
    const _Float16* xb = xpair + (long)b * FEAT_PER_B;
    const uint4* xa[5];
#pragma unroll
    for (int p = 0; p < 5; ++p) xa[p] = (const uint4*)(xb + p * 3072);

    float h = 0.0f;
    uint4 xq0[5], xq1[5];
#pragma unroll
    for (int p = 0; p < 5; ++p) xq0[p] = xa[p][0];

    // 384 chunks of 4 steps, ping-pong pairs (xq0/xq1 alternate roles — no
    // register rotation [R18]). 384 is even; prefetch c2+1 always in range,
    // tail prefetch c2+2 clamps to 383.
    for (int c2 = 0; c2 < 384; c2 += 2) {
#pragma unroll
        for (int p = 0; p < 5; ++p) xq1[p] = xa[p][c2 + 1];
        STEP(xq0, 0);
        STEP(xq0, 1);
        STEP(xq0, 2);
        STEP(xq0, 3);
        const int cn = (c2 + 2 < 384) ? (c2 + 2) : 383;
#pragma unroll
        for (int p = 0; p < 5; ++p) xq0[p] = xa[p][cn];
        STEP(xq1, 0);
        STEP(xq1, 1);
        STEP(xq1, 2);
        STEP(xq1, 3);
    }

    // out[b] = relu(h . W_out + b_out), reduced within each 32-lane half
    float v = active ? h * W_out[kk] : 0.0f;
#pragma unroll
    for (int off = 16; off; off >>= 1) v += __shfl_xor(v, off, 32);
    if (k == 0) {
        float o = v + b_out[0];
        out[b] = o > 0.0f ? o : 0.0f;
    }
}

extern "C" void kernel_launch(void* const* d_in, const int* in_sizes, int n_in,
                              void* d_out, int out_size, void* d_ws, size_t ws_size,
                              hipStream_t stream) {
    const int* atom_i   = (const int*)d_in[0];
    const int* atom_j   = (const int*)d_in[1];
    const float* dist   = (const float*)d_in[2];
    const float* emb    = (const float*)d_in[3];
    const float* W_ih   = (const float*)d_in[4];
    const float* W_hh   = (const float*)d_in[5];
    const float* b_ih   = (const float*)d_in[6];
    const float* b_hh   = (const float*)d_in[7];
    const float* W_out  = (const float*)d_in[8];
    const float* b_out  = (const float*)d_in[9];
    float* out = (float*)d_out;
    _Float16* xpair = (_Float16*)d_ws;   // 62,914,560 B

    feat_kernel<<<BATCH, 512, 0, stream>>>(atom_i, atom_j, dist, emb,
                                           (uint4*)xpair);
    gru_kernel<<<BATCH / 2, 64, 0, stream>>>(xpair, W_ih, W_hh, b_ih, b_hh,
                                             W_out, b_out, out);
}